// Round 11
// baseline (352.242 us; speedup 1.0000x reference)
//
#include <hip/hip_runtime.h>

#define NT   49      // tokens per window
#define HD   32      // head dim
#define NH   4
#define DIM  128
#define SCALEQ 0.17677669529663687f  // 32^-0.5

typedef __attribute__((ext_vector_type(8))) short short8;
typedef __attribute__((ext_vector_type(4))) short short4v;
typedef __attribute__((ext_vector_type(4))) float floatx4;
// may_alias versions: all LDS/global type-punned accesses go through these so
// TBAA cannot reorder stores/loads across the barrier-free phase chain.
typedef short8 short8a __attribute__((may_alias));
typedef short4v short4a __attribute__((may_alias));
typedef unsigned long long ulla __attribute__((may_alias));
typedef unsigned long long ull;

// Conversions: hand-rolled RNE fp32->bf16 (bit-exact across all passing runs).
// Quarantined: <hip/hip_bf16.h> (R6/R7 container deaths) and inline-asm
// v_cvt_pk_bf16_f32 (R8 NaN). Do not reintroduce without isolated A/B.
__device__ __forceinline__ short f2b(float f) {
    union { float f; unsigned u; } v; v.f = f;
    return (short)((v.u + 0x7fffu + ((v.u >> 16) & 1u)) >> 16);  // RNE fp32->bf16
}
__device__ __forceinline__ ull pk4(float a, float b, float c, float d) {
    return  (ull)(unsigned short)f2b(a)
         | ((ull)(unsigned short)f2b(b) << 16)
         | ((ull)(unsigned short)f2b(c) << 32)
         | ((ull)(unsigned short)f2b(d) << 48);
}
__device__ __forceinline__ float b2f(short s) {
    union { unsigned u; float f; } v; v.u = ((unsigned)(unsigned short)s) << 16;
    return v.f;
}

// K=16 MFMA (A[row=cc][k=qq*4+e], B[col=cc][k=qq*4+e]) — HW-validated R3-R10.
// Fallback: zero-padded K=32 (elements at e=0..3 map to k32=qq*8+e identically
// for A and B, so the contraction equals the K=16 product).
#if __has_builtin(__builtin_amdgcn_mfma_f32_16x16x16bf16_1k)
__device__ __forceinline__ floatx4 MFMA16(short4v a, short4v b, floatx4 c) {
    return __builtin_amdgcn_mfma_f32_16x16x16bf16_1k(a, b, c, 0, 0, 0);
}
#else
__device__ __forceinline__ floatx4 MFMA16(short4v a, short4v b, floatx4 c) {
    short8 a8 = {a[0], a[1], a[2], a[3], 0, 0, 0, 0};
    short8 b8 = {b[0], b[1], b[2], b[3], 0, 0, 0, 0};
    return __builtin_amdgcn_mfma_f32_16x16x32_bf16(a8, b8, c, 0, 0, 0);
}
#endif

// ---------- prologue ----------
// 64 blocks (one per window). Stage ridx/btab/mask in LDS, emit the combined
// bias+mask table (cmb) in MFMA frag layout + convert weights to bf16.
// cmb[wdw][h][(it*4+jt)*256 + qq*64 + cc*4 + r] bf16 = bias[h] + mask[wdw];
// col>=49 -> -1e30 (masks key pads via C-init), row>=49 -> 0. wqkv Q-section
// pre-scaled by hd^-0.5.
__global__ __launch_bounds__(256) void wmsa_prep(
        const float* __restrict__ qkvw, const float* __restrict__ projw,
        const float* __restrict__ btab, const int* __restrict__ ridx,
        const float* __restrict__ mask,
        short* __restrict__ wqkv, short* __restrict__ wproj,
        short* __restrict__ cmb) {
    __shared__ __align__(16) int   s_ridx[NT * NT];        // 9604 B
    __shared__ __align__(16) float s_btab[169 * 4];        // 2704 B (float4 rows)
    __shared__ __align__(16) float s_mask[NT * NT];        // 9604 B

    const int wdw = blockIdx.x;
    const int tid = threadIdx.x;

    // ---- weight conversion: one float4 group per thread (grid covers all) ----
    {
        int g = wdw * 256 + tid;          // 0..16383; 3*128*128/4 = 12288 qkv groups
        const float* src = (g < 12288) ? (qkvw + g * 4) : (projw + (g - 12288) * 4);
        float4 v = *(const float4*)src;
        float s = (g < 4096) ? SCALEQ : 1.0f;   // first DIM*DIM elements = Q rows
        ull pk = pk4(v.x * s, v.y * s, v.z * s, v.w * s);
        if (g < 12288) *(ulla*)(wqkv + g * 4) = pk;
        else           *(ulla*)(wproj + (g - 12288) * 4) = pk;
    }

    // ---- stage gather tables (coalesced) ----
    for (int i = tid; i < NT * NT; i += 256) s_ridx[i] = ridx[i];
    for (int i = tid; i < 169 * 4; i += 256) s_btab[i] = btab[i];
    {
        const float* mw = mask + (size_t)wdw * NT * NT;
        for (int i = tid; i < NT * NT; i += 256) s_mask[i] = mw[i];
    }
    __syncthreads();

    // ---- emit combined table for this window: 4 heads x 4096 bf16 ----
    // group g encodes (it,jt,qq,cc); the 4 consecutive shorts are r=0..3.
    #pragma unroll
    for (int gi = 0; gi < 4; ++gi) {
        int g = gi * 256 + tid;                       // 0..1023
        int cc = g & 15, qq = (g >> 4) & 3, tile = g >> 6;
        int it = tile >> 2, jt = tile & 3;
        int col = jt * 16 + cc;
        int rowb = it * 16 + qq * 4;
        if (col >= NT) {
            ull m16 = (unsigned short)f2b(-1e30f);
            ull pk = m16 | (m16 << 16) | (m16 << 32) | (m16 << 48);
            #pragma unroll
            for (int h = 0; h < NH; ++h)
                *(ulla*)(cmb + (((size_t)wdw * NH + h) << 12) + g * 4) = pk;
        } else {
            float bt[4][4], mv[4];
            #pragma unroll
            for (int r = 0; r < 4; ++r) {
                int row = rowb + r;
                if (row >= NT) {
                    bt[r][0] = bt[r][1] = bt[r][2] = bt[r][3] = 0.f;
                    mv[r] = 0.f;
                } else {
                    int ri = s_ridx[row * NT + col];
                    float4 b4 = *(const float4*)(s_btab + ri * 4);  // all 4 heads
                    bt[r][0] = b4.x; bt[r][1] = b4.y; bt[r][2] = b4.z; bt[r][3] = b4.w;
                    mv[r] = s_mask[row * NT + col];
                }
            }
            #pragma unroll
            for (int h = 0; h < NH; ++h) {
                ull pk = pk4(bt[0][h] + mv[0], bt[1][h] + mv[1],
                             bt[2][h] + mv[2], bt[3][h] + mv[3]);
                *(ulla*)(cmb + (((size_t)wdw * NH + h) << 12) + g * 4) = pk;
            }
        }
    }
}

// R11: 512-thread blocks, 8 waves = 4 heads x 2 row-halves. Wave (h, rh)
// handles it/tt tiles {rh*2, rh*2+1} of head h — per-wave serial chain
// halves, af drops to 32 VGPRs. Target: VGPR <= 64 so HW allows 8 waves/SIMD;
// LDS 51200 -> 3 blocks x 8 waves = 24 waves/CU (75% cap) vs R10's ~16 (41%).
// V returns to LDS (R4's verified [32][72] packed layout) because the PV
// contraction needs all 4 token tiles, now split across the wave pair. New
// barrier B3 makes Q/K/V cross-wave visible; P stays SAME-WAVE (phase-3 tt
// tiles read exactly the P rows this wave wrote) -> intra-wave fence suffices.
// Per-head region at h*12800: Q 4096 | K 4096 | V 4608; P [64][64] (8192)
// overlays Q+K after S. X/O [64][136]=17408 overlay pool base phase-disjointly.
// Perf ledger: R4=155, R9 reg-QK=166, R10 (R4+O^T epi)=153. Spill signature:
// WRITE>>100MB. launch_bounds(512,6) -> 85-reg cap (no spill risk; demand ~60).
#define RHEAD 12800
#define OSTR  136
#define LDSB  51200

__global__ __launch_bounds__(512, 6) void wmsa_main(
    const float* __restrict__ x,
    const float* __restrict__ qkvb, const float* __restrict__ projb,
    const short* __restrict__ wqkv, const short* __restrict__ wproj,
    const short* __restrict__ cmb, float* __restrict__ out)
{
    __shared__ __align__(16) char pool[LDSB];
    short* lds = (short*)pool;

    const int b    = blockIdx.x;
    const int wdw  = b & 63;
    const int tid  = threadIdx.x;
    const int wave = tid >> 6;
    const int h    = wave >> 1;        // head 0..3
    const int rh   = wave & 1;         // row-half: tiles {rh*2, rh*2+1}
    const int lane = tid & 63;
    const int qq   = lane >> 4;        // quad 0..3
    const int cc   = lane & 15;
    const int ccl  = cc & 7, cch = cc >> 3, cm3 = cc & 3;
    const int colbase = h * 32 + cc;

    // ---------------- Phase 0: stage x -> bf16 LDS (stride 136), zero pad rows ----------------
    {
        const float* xb = x + (size_t)b * NT * DIM;
        for (int i = tid; i < NT * 32; i += 512) {
            int t = i >> 5, c4 = (i & 31) << 2;
            float4 v = *(const float4*)(xb + t * DIM + c4);
            *(ulla*)(lds + t * 136 + c4) = pk4(v.x, v.y, v.z, v.w);
        }
        for (int i = tid; i < (64 - NT) * 32; i += 512) {   // zero rows 49..63
            int t = NT + (i >> 5), c4 = (i & 31) << 2;
            *(ulla*)(lds + t * 136 + c4) = 0ull;
        }
    }
    __syncthreads();   // B1: X staged

    // A-frags of X for THIS WAVE's 2 row tiles only (32 VGPRs, was 64)
    short8 af[2][4];
    #pragma unroll
    for (int j = 0; j < 2; ++j)
        #pragma unroll
        for (int ks = 0; ks < 4; ++ks)
            af[j][ks] = *(const short8a*)(lds + ((rh * 2 + j) * 16 + cc) * 136 + ks * 32 + qq * 8);
    __syncthreads();   // B2: X reads done; per-head regions may be written

    short* qw = (short*)(pool + h * RHEAD);
    short* kw = qw + 2048;     // +4096 B
    short* vw = qw + 4096;     // +8192 B, V [32 dims][72 tokens]
    short* pw = qw;            // P overlays Q+K after S

    // ---------------- Phase 1: wave (h,rh) computes its half of Q/K/V of head h ----------------
    #pragma unroll
    for (int jt6 = 0; jt6 < 6; ++jt6) {
        const int sec = jt6 >> 1, hlf = jt6 & 1;             // compile-time
        short8 bfc[4];
        {
            const int cn = sec * DIM + colbase + hlf * 16;
            #pragma unroll
            for (int ks = 0; ks < 4; ++ks)
                bfc[ks] = *(const short8a*)(wqkv + cn * DIM + ks * 32 + qq * 8);
        }
        float bias = qkvb[sec * DIM + colbase + hlf * 16];   // per output col (L1-hot)
        if (sec == 0) bias *= SCALEQ;
        const floatx4 cinit = {bias, bias, bias, bias};
        #pragma unroll
        for (int j = 0; j < 2; ++j) {
            const int its = rh * 2 + j;
            floatx4 acc = cinit;
            #pragma unroll
            for (int ks = 0; ks < 4; ++ks)
                acc = __builtin_amdgcn_mfma_f32_16x16x32_bf16(af[j][ks], bfc[ks], acc, 0, 0, 0);
            if (sec == 2) {                                   // V: packed 4 tokens
                int dd = hlf * 16 + cc;
                int t0 = its * 16 + qq * 4;
                *(ulla*)(vw + dd * 72 + t0) = pk4(acc[0], acc[1], acc[2], acc[3]);
            } else {                                          // Q/K: [t][d] swizzled
                short* dst = (sec == 0) ? qw : kw;
                int gb = hlf * 2 + cch;                       // d>>3
                #pragma unroll
                for (int r = 0; r < 4; ++r) {                 // t&3 == r
                    int t = its * 16 + qq * 4 + r;
                    dst[t * 32 + ((gb ^ r) << 3) + ccl] = f2b(acc[r]);
                }
            }
        }
    }

    // prefetch this wave's 8 S-tile C-inits (bias+mask, bf16 frag layout)
    short4v cm[2][4];
    {
        const short* cw = cmb + (((size_t)wdw * NH + h) << 12);
        #pragma unroll
        for (int j = 0; j < 2; ++j)
            #pragma unroll
            for (int jt = 0; jt < 4; ++jt)
                cm[j][jt] = *(const short4a*)(cw + ((rh * 2 + j) * 4 + jt) * 256 + qq * 64 + cc * 4);
    }
    __syncthreads();   // B3 (NEW): Q/K/V visible across the head's wave pair

    // ---------------- Phase 2: S rows for this wave's 2 tiles, exp, store RAW P ----------------
    // P stored UNNORMALIZED (rowsum via ones-MFMA in phase 3). 3-bit swizzle:
    // g = (col>>3) ^ (t&3) ^ (((t>>2)&1)<<2). Formulas verbatim from R10.
    {
        short8 qf[2], kf[4];
        #pragma unroll
        for (int j = 0; j < 2; ++j)
            qf[j] = *(const short8a*)(qw + ((rh * 2 + j) * 16 + cc) * 32 + ((qq ^ cm3) << 3));
        #pragma unroll
        for (int t = 0; t < 4; ++t)
            kf[t] = *(const short8a*)(kw + (t * 16 + cc) * 32 + ((qq ^ cm3) << 3));
        #pragma unroll
        for (int j = 0; j < 2; ++j) {
            const int its = rh * 2 + j;
            floatx4 s[4];
            #pragma unroll
            for (int jt = 0; jt < 4; ++jt) {
                short4v cb = cm[j][jt];
                floatx4 ci = {b2f(cb.x), b2f(cb.y), b2f(cb.z), b2f(cb.w)};
                s[jt] = __builtin_amdgcn_mfma_f32_16x16x32_bf16(qf[j], kf[jt], ci, 0, 0, 0);
            }
            #pragma unroll
            for (int r = 0; r < 4; ++r) {
                int t = its * 16 + qq * 4 + r;
                #pragma unroll
                for (int jt = 0; jt < 4; ++jt) {
                    float ee = __expf(s[jt][r]);   // pads -> exp(-1e30)=0
                    int g = (jt * 2 + cch) ^ r ^ ((qq & 1) << 2);
                    pw[t * 64 + (g << 3) + ccl] = f2b(ee);
                }
            }
        }
    }
    __asm__ volatile("" ::: "memory");   // intra-wave fence: P stores -> PV loads (same-wave rows)

    // ---------------- Phase 3: O^T = V^T P^T + rowsum, for this wave's 2 tt tiles ----------------
    // o[hlf][j]: lane holds O^T[d=h*32+hlf*16+qq*4+r][t=(rh*2+j)*16+cc].
    // V A-frag read: V^T[d=hlf*16+cc][tok k4*16+qq*4+e] = vw[(hlf*16+cc)*72 + ...] b64.
    floatx4 o[2][2];
    const short BONE = (short)0x3F80;    // bf16 1.0
    const short4v ones4 = {BONE, BONE, BONE, BONE};
    #pragma unroll
    for (int j = 0; j < 2; ++j) {
        const int tt = rh * 2 + j;
        short4v ptb[4];
        #pragma unroll
        for (int k4 = 0; k4 < 4; ++k4) {
            int g = (k4 * 2 + (qq >> 1)) ^ cm3 ^ (((cc >> 2) & 1) << 2);
            ptb[k4] = *(const short4a*)(pw + (tt * 16 + cc) * 64 + (g << 3) + (qq & 1) * 4);
        }
        floatx4 a0 = {0.f, 0.f, 0.f, 0.f}, a1 = a0, smv = a0;
        #pragma unroll
        for (int k4 = 0; k4 < 4; ++k4) {
            short4v v0 = *(const short4a*)(vw + cc * 72 + k4 * 16 + qq * 4);
            short4v v1 = *(const short4a*)(vw + (16 + cc) * 72 + k4 * 16 + qq * 4);
            a0  = MFMA16(v0, ptb[k4], a0);
            a1  = MFMA16(v1, ptb[k4], a1);
            smv = MFMA16(ones4, ptb[k4], smv);
        }
        float inv = 1.0f / smv[0];       // all 4 rows of smv identical
        #pragma unroll
        for (int r = 0; r < 4; ++r) { a0[r] *= inv; a1[r] *= inv; }
        o[0][j] = a0; o[1][j] = a1;
    }

    // prefetch proj B-frags (jt=0 of this wave's col-half) + 4 proj biases
    short8 pcur[4], pnxt[4];
    float pbv[4];
    #pragma unroll
    for (int ks = 0; ks < 4; ++ks)
        pcur[ks] = *(const short8a*)(wproj + (rh * 64 + cc) * DIM + ks * 32 + qq * 8);
    #pragma unroll
    for (int j = 0; j < 4; ++j) pbv[j] = projb[rh * 64 + j * 16 + cc];

    __syncthreads();   // B4: all P/V reads done -> O may overlay pool base

    // O store: packed b64, 4 consecutive features per write (4 writes/lane)
    short* ow = (short*)pool;   // O [64 tokens][OSTR=136], features 0..127
    #pragma unroll
    for (int hlf = 0; hlf < 2; ++hlf)
        #pragma unroll
        for (int j = 0; j < 2; ++j) {
            int t  = (rh * 2 + j) * 16 + cc;
            int f0 = h * 32 + hlf * 16 + qq * 4;
            *(ulla*)(ow + t * OSTR + f0) =
                pk4(o[hlf][j][0], o[hlf][j][1], o[hlf][j][2], o[hlf][j][3]);
        }
    __syncthreads();   // B5: O visible

    // ---------------- Phase 4: proj GEMM — wave does row tile h, col half rh ----------------
    {
        short8 a2[4];
        #pragma unroll
        for (int ks = 0; ks < 4; ++ks)
            a2[ks] = *(const short8a*)(ow + (h * 16 + cc) * OSTR + ks * 32 + qq * 8);
        float* outb = out + (size_t)b * NT * DIM;
        #pragma unroll
        for (int jt = 0; jt < 4; ++jt) {
            if (jt < 3) {
                int cn = rh * 64 + (jt + 1) * 16 + cc;
                #pragma unroll
                for (int ks = 0; ks < 4; ++ks)
                    pnxt[ks] = *(const short8a*)(wproj + cn * DIM + ks * 32 + qq * 8);
            }
            float pb = pbv[jt];
            floatx4 acc = {pb, pb, pb, pb};
            #pragma unroll
            for (int ks = 0; ks < 4; ++ks)
                acc = __builtin_amdgcn_mfma_f32_16x16x32_bf16(a2[ks], pcur[ks], acc, 0, 0, 0);
            int col = rh * 64 + jt * 16 + cc;
            #pragma unroll
            for (int r = 0; r < 4; ++r) {
                int row = h * 16 + qq * 4 + r;
                if (row < NT) outb[row * DIM + col] = acc[r];
            }
            #pragma unroll
            for (int ks = 0; ks < 4; ++ks) pcur[ks] = pnxt[ks];
        }
    }
}

extern "C" void kernel_launch(void* const* d_in, const int* in_sizes, int n_in,
                              void* d_out, int out_size, void* d_ws, size_t ws_size,
                              hipStream_t stream) {
    const float* x     = (const float*)d_in[0];   // (4096,49,128)
    const float* mask  = (const float*)d_in[1];   // (64,49,49)
    const float* qkvw  = (const float*)d_in[2];   // (384,128)
    const float* qkvb  = (const float*)d_in[3];   // (384)
    const float* projw = (const float*)d_in[4];   // (128,128)
    const float* projb = (const float*)d_in[5];   // (128)
    const float* btab  = (const float*)d_in[6];   // (169,4)
    const int*   ridx  = (const int*)d_in[7];     // (49,49)
    float* outp = (float*)d_out;

    short* wqkv  = (short*)d_ws;                      //   98304 B
    short* wproj = (short*)((char*)d_ws + 98304);     //   32768 B
    short* cmb   = (short*)((char*)d_ws + 131072);    // 2097152 B (total 2.23 MB)

    wmsa_prep<<<64, 256, 0, stream>>>(qkvw, projw, btab, ridx, mask, wqkv, wproj, cmb);
    wmsa_main<<<4096, 512, 0, stream>>>(x, qkvb, projb, wqkv, wproj, cmb, outp);
}